// Round 1
// baseline (143.467 us; speedup 1.0000x reference)
//
#include <hip/hip_runtime.h>
#include <math.h>

#define T_TOTAL 8192
#define D_TOTAL 4096
#define E 64
#define TOPK 8

#define TB 32      // tokens per block (kernel 1)
#define DK 64      // K chunk staged in LDS
#define XPAD 4
#define WPAD 4

// ---------------- Kernel 1: logits partial GEMM ----------------
// grid: (T_TOTAL/TB, S). Each block computes partial logits for 32 tokens x
// 64 experts over its D-chunk, writes fp32 partials to ws[s][t][e].
__global__ __launch_bounds__(256, 4)
void gemm_logits(const float* __restrict__ x, const float* __restrict__ w,
                 float* __restrict__ part, int dchunk) {
    __shared__ __align__(16) float xs[TB][DK + XPAD];     // 32 x 68
    __shared__ __align__(16) float wsm[E][DK + WPAD];     // 64 x 68

    const int tid = threadIdx.x;
    const int tok0 = blockIdx.x * TB;
    const int d0 = blockIdx.y * dchunk;

    // compute mapping: 16 expert-groups x 16 token-pairs
    const int et = tid & 15;         // experts et, et+16, et+32, et+48
    const int tt = tid >> 4;         // tokens 2*tt, 2*tt+1

    float acc[2][4];
#pragma unroll
    for (int i = 0; i < 2; ++i)
#pragma unroll
        for (int j = 0; j < 4; ++j) acc[i][j] = 0.f;

    // staging mapping
    const int srow = tid >> 4;       // 0..15
    const int scol = tid & 15;       // float4 column 0..15

    for (int kc = 0; kc < dchunk; kc += DK) {
        __syncthreads();
        // stage x tile: 32 rows x 16 float4
#pragma unroll
        for (int r = 0; r < 2; ++r) {
            const int row = srow + 16 * r;
            const float4 v = *reinterpret_cast<const float4*>(
                &x[(size_t)(tok0 + row) * D_TOTAL + d0 + kc + scol * 4]);
            *reinterpret_cast<float4*>(&xs[row][scol * 4]) = v;
        }
        // stage w tile: 64 rows x 16 float4
#pragma unroll
        for (int r = 0; r < 4; ++r) {
            const int row = srow + 16 * r;
            const float4 v = *reinterpret_cast<const float4*>(
                &w[(size_t)row * D_TOTAL + d0 + kc + scol * 4]);
            *reinterpret_cast<float4*>(&wsm[row][scol * 4]) = v;
        }
        __syncthreads();

#pragma unroll
        for (int kk = 0; kk < DK; kk += 4) {
            const float4 xa = *reinterpret_cast<const float4*>(&xs[2 * tt + 0][kk]);
            const float4 xb = *reinterpret_cast<const float4*>(&xs[2 * tt + 1][kk]);
#pragma unroll
            for (int j = 0; j < 4; ++j) {
                const float4 wv = *reinterpret_cast<const float4*>(&wsm[et + 16 * j][kk]);
                acc[0][j] = fmaf(xa.x, wv.x, acc[0][j]);
                acc[0][j] = fmaf(xa.y, wv.y, acc[0][j]);
                acc[0][j] = fmaf(xa.z, wv.z, acc[0][j]);
                acc[0][j] = fmaf(xa.w, wv.w, acc[0][j]);
                acc[1][j] = fmaf(xb.x, wv.x, acc[1][j]);
                acc[1][j] = fmaf(xb.y, wv.y, acc[1][j]);
                acc[1][j] = fmaf(xb.z, wv.z, acc[1][j]);
                acc[1][j] = fmaf(xb.w, wv.w, acc[1][j]);
            }
        }
    }

    // write partials: part[ds][tok][e]
    float* pbase = part + ((size_t)blockIdx.y * T_TOTAL + tok0) * E;
#pragma unroll
    for (int i = 0; i < 2; ++i) {
        const int t = 2 * tt + i;
#pragma unroll
        for (int j = 0; j < 4; ++j) {
            pbase[(size_t)t * E + et + 16 * j] = acc[i][j];
        }
    }
}

// ---------------- Kernel 2: sum partials + sigmoid + top-8 ----------------
// grid: T_TOTAL/32 blocks of 256 threads. Block handles 32 tokens.
__global__ __launch_bounds__(256)
void topk_kernel(const float* __restrict__ part, float* __restrict__ out, int S) {
    __shared__ float lg[32][E + 1];

    const int tid = threadIdx.x;
    const int tok0 = blockIdx.x * 32;
    const size_t base = (size_t)tok0 * E;

    // cooperative, coalesced accumulation of 32x64 logits
    const int f = tid * 8;  // 2048 floats / 256 threads = 8 each
    float4 v0 = make_float4(0.f, 0.f, 0.f, 0.f);
    float4 v1 = make_float4(0.f, 0.f, 0.f, 0.f);
    for (int s = 0; s < S; ++s) {
        const float4* p = reinterpret_cast<const float4*>(
            part + (size_t)s * T_TOTAL * E + base + f);
        const float4 a = p[0];
        const float4 b = p[1];
        v0.x += a.x; v0.y += a.y; v0.z += a.z; v0.w += a.w;
        v1.x += b.x; v1.y += b.y; v1.z += b.z; v1.w += b.w;
    }
    {
        const int t = f >> 6;
        const int e = f & 63;
        lg[t][e + 0] = v0.x; lg[t][e + 1] = v0.y; lg[t][e + 2] = v0.z; lg[t][e + 3] = v0.w;
        lg[t][e + 4] = v1.x; lg[t][e + 5] = v1.y; lg[t][e + 6] = v1.z; lg[t][e + 7] = v1.w;
    }
    __syncthreads();

    if (tid < 32) {
        const int t = tid;
        float bv[TOPK];
        int   bi[TOPK];
#pragma unroll
        for (int j = 0; j < TOPK; ++j) { bv[j] = -INFINITY; bi[j] = 0; }

        // top-k on raw logits (sigmoid is monotonic); stable ties (strict >)
        for (int e = 0; e < E; ++e) {
            const float v = lg[t][e];
            if (v > bv[TOPK - 1]) {
                // branchless sorted insert, fully unrolled (registers only)
#pragma unroll
                for (int j = TOPK - 1; j > 0; --j) {
                    const bool gt = v > bv[j];
                    const bool gtp = v > bv[j - 1];
                    const float nv = gt ? (gtp ? bv[j - 1] : v) : bv[j];
                    const int   ni = gt ? (gtp ? bi[j - 1] : e) : bi[j];
                    bv[j] = nv; bi[j] = ni;
                }
                if (v > bv[0]) { bv[0] = v; bi[0] = e; }
            }
        }

        float wv[TOPK];
        float wsum = 0.f;
#pragma unroll
        for (int j = 0; j < TOPK; ++j) {
            wv[j] = 1.f / (1.f + expf(-bv[j]));
            wsum += wv[j];
        }
        const float inv = 1.f / fmaxf(wsum, 1e-12f);

        const int tg = tok0 + t;
#pragma unroll
        for (int j = 0; j < TOPK; ++j) {
            out[(size_t)tg * TOPK + j] = wv[j] * inv;
        }
#pragma unroll
        for (int j = 0; j < TOPK; ++j) {
            out[(size_t)T_TOTAL * TOPK + (size_t)tg * TOPK + j] = (float)bi[j];
        }
    }
}

extern "C" void kernel_launch(void* const* d_in, const int* in_sizes, int n_in,
                              void* d_out, int out_size, void* d_ws, size_t ws_size,
                              hipStream_t stream) {
    const float* x = (const float*)d_in[0];
    const float* w = (const float*)d_in[1];
    float* out = (float*)d_out;
    float* part = (float*)d_ws;

    // choose D-split by available workspace (S*T*E*4 bytes of partials)
    int S = 4;
    if (ws_size < (size_t)4 * T_TOTAL * E * sizeof(float)) {
        S = (ws_size >= (size_t)2 * T_TOTAL * E * sizeof(float)) ? 2 : 1;
    }
    const int dchunk = D_TOTAL / S;

    dim3 g1(T_TOTAL / TB, S);
    gemm_logits<<<g1, 256, 0, stream>>>(x, w, part, dchunk);
    topk_kernel<<<T_TOTAL / 32, 256, 0, stream>>>(part, out, S);
}